// Round 1
// baseline (651.930 us; speedup 1.0000x reference)
//
#include <hip/hip_runtime.h>
#include <stdint.h>

#define L_SEQ 50
#define D_EMB 128
#define UPB   5   // users per block

typedef __attribute__((ext_vector_type(8))) short bf16x8;
typedef __attribute__((ext_vector_type(4))) float f32x4;

__device__ __forceinline__ short f2bf(float f) {
    union { float f; uint32_t u; } c;
    c.f = f;
    uint32_t r = c.u + 0x7FFFu + ((c.u >> 16) & 1u);  // RNE
    return (short)(r >> 16);
}

__device__ __forceinline__ bf16x8 pack2(float4 a, float4 b) {
    bf16x8 r;
    r[0] = f2bf(a.x); r[1] = f2bf(a.y); r[2] = f2bf(a.z); r[3] = f2bf(a.w);
    r[4] = f2bf(b.x); r[5] = f2bf(b.y); r[6] = f2bf(b.z); r[7] = f2bf(b.w);
    return r;
}

__device__ __forceinline__ float tanh_fast(float x) {
    // tanh(x) = 1 - 2/(e^{2x}+1); exact at +-inf, fine for |x| small (our case)
    float e = __expf(2.0f * x);
    return 1.0f - 2.0f / (e + 1.0f);
}

#define MFMA16(a, b, c) __builtin_amdgcn_mfma_f32_16x16x32_bf16((a), (b), (c), 0, 0, 0)

__global__ void finerec_fused(
    const float* __restrict__ item_table,
    const float* __restrict__ opin_table,
    const float* __restrict__ user_emb,
    const float* __restrict__ attr,
    const float* __restrict__ Wq, const float* __restrict__ bq,
    const float* __restrict__ Wk, const float* __restrict__ bk,
    const float* __restrict__ Wv, const float* __restrict__ bv,
    const int* __restrict__ item_seqs,
    const int* __restrict__ opin_seqs,
    float* __restrict__ out, int U)
{
    __shared__ float attr_s[D_EMB];
    __shared__ float q_s[D_EMB];
    __shared__ float w4[4][64];
    __shared__ float w_s[64];
    __shared__ int   its[64];
    __shared__ int   ots[64];

    const int tid  = threadIdx.x;
    const int wv   = tid >> 6;    // wave 0..3, owns N-cols [32*wv, 32*wv+32)
    const int lane = tid & 63;
    const int l15  = lane & 15;
    const int quad = lane >> 4;

    if (tid < D_EMB) attr_s[tid] = attr[tid];

    // ---- B fragments (weights as W[n][k] == B^T rows), loaded once per block ----
    // B-frag lane layout: n = ntile*16 + (lane&15), k = ks*32 + (lane>>4)*8 + j
    bf16x8 wqf[2][4], wkf[2][4], wvf[2][4];
    float  bqf[2], bkf[2], bvf[2];
#pragma unroll
    for (int nt = 0; nt < 2; ++nt) {
        const int n = (2 * wv + nt) * 16 + l15;
        bqf[nt] = bq[n]; bkf[nt] = bk[n]; bvf[nt] = bv[n];
#pragma unroll
        for (int ks = 0; ks < 4; ++ks) {
            const int kb = ks * 32 + quad * 8;
            const float4* pq = (const float4*)(Wq + n * D_EMB + kb);
            const float4* pk = (const float4*)(Wk + n * D_EMB + kb);
            const float4* pv = (const float4*)(Wv + n * D_EMB + kb);
            wqf[nt][ks] = pack2(pq[0], pq[1]);
            wkf[nt][ks] = pack2(pk[0], pk[1]);
            wvf[nt][ks] = pack2(pv[0], pv[1]);
        }
    }
    __syncthreads();

    for (int uu = 0; uu < UPB; ++uu) {
        const int u = blockIdx.x * UPB + uu;
        if (u >= U) break;  // block-uniform

        if (tid < 64) {
            its[tid] = (tid < L_SEQ) ? item_seqs[u * L_SEQ + tid] : 0;
            ots[tid] = (tid < L_SEQ) ? opin_seqs[u * L_SEQ + tid] : 0;
        }
        __syncthreads();

        // ---------- q = tanh(user @ Wq^T + bq), single row via M-tile row 0 ----------
        f32x4 accq0 = {0,0,0,0}, accq1 = {0,0,0,0};
#pragma unroll
        for (int ks = 0; ks < 4; ++ks) {
            const int kb = ks * 32 + quad * 8;
            bf16x8 af = {0,0,0,0,0,0,0,0};
            if (l15 == 0) {
                const float4* p = (const float4*)(user_emb + u * D_EMB + kb);
                af = pack2(p[0], p[1]);
            }
            accq0 = MFMA16(af, wqf[0][ks], accq0);
            accq1 = MFMA16(af, wqf[1][ks], accq1);
        }
        // C layout: col = lane&15, row = quad*4 + reg ; row 0 lives in lanes<16, reg 0
        if (lane < 16) {
            q_s[(2 * wv + 0) * 16 + lane] = tanh_fast(accq0[0] + bqf[0]);
            q_s[(2 * wv + 1) * 16 + lane] = tanh_fast(accq1[0] + bqf[1]);
        }
        __syncthreads();
        const float qf0 = q_s[(2 * wv + 0) * 16 + l15];
        const float qf1 = q_s[(2 * wv + 1) * 16 + l15];

        // ---------- k = tanh((attr+item) @ Wk^T + bk); w = q . k ----------
#pragma unroll
        for (int m = 0; m < 4; ++m) {
            const int rowA = m * 16 + l15;
            const int idx  = its[rowA];     // padded rows use row 0 (masked later)
            f32x4 a0 = {0,0,0,0}, a1 = {0,0,0,0};
#pragma unroll
            for (int ks = 0; ks < 4; ++ks) {
                const int kb = ks * 32 + quad * 8;
                const float4* pi = (const float4*)(item_table + (size_t)idx * D_EMB + kb);
                float4 i0 = pi[0], i1 = pi[1];
                float4 t0 = *(const float4*)(attr_s + kb);
                float4 t1 = *(const float4*)(attr_s + kb + 4);
                i0.x += t0.x; i0.y += t0.y; i0.z += t0.z; i0.w += t0.w;
                i1.x += t1.x; i1.y += t1.y; i1.z += t1.z; i1.w += t1.w;
                bf16x8 af = pack2(i0, i1);
                a0 = MFMA16(af, wkf[0][ks], a0);
                a1 = MFMA16(af, wkf[1][ks], a1);
            }
#pragma unroll
            for (int r = 0; r < 4; ++r) {
                float k0 = tanh_fast(a0[r] + bkf[0]);
                float k1 = tanh_fast(a1[r] + bkf[1]);
                float s  = k0 * qf0 + k1 * qf1;           // partial over this wave's 32 cols
                s += __shfl_xor(s, 1);
                s += __shfl_xor(s, 2);
                s += __shfl_xor(s, 4);
                s += __shfl_xor(s, 8);                    // sum over 16 cols in group
                if (l15 == 0) w4[wv][m * 16 + quad * 4 + r] = s;
            }
        }
        __syncthreads();
        if (tid < 64) {
            float s = w4[0][tid] + w4[1][tid] + w4[2][tid] + w4[3][tid];
            w_s[tid] = (its[tid] > 0) ? s : 0.0f;        // mask + padding kill
        }
        __syncthreads();

        // ---------- v = tanh((item+opin) @ Wv^T + bv); out = sum_l w[l]*v[l] ----------
        float o0 = 0.0f, o1 = 0.0f;
#pragma unroll
        for (int m = 0; m < 4; ++m) {
            const int rowA = m * 16 + l15;
            const int idx  = its[rowA];
            const int odx  = ots[rowA];
            f32x4 a0 = {0,0,0,0}, a1 = {0,0,0,0};
#pragma unroll
            for (int ks = 0; ks < 4; ++ks) {
                const int kb = ks * 32 + quad * 8;
                const float4* pi = (const float4*)(item_table + (size_t)idx * D_EMB + kb);
                const float4* po = (const float4*)(opin_table + (size_t)odx * D_EMB + kb);
                float4 i0 = pi[0], i1 = pi[1];
                float4 t0 = po[0], t1 = po[1];
                i0.x += t0.x; i0.y += t0.y; i0.z += t0.z; i0.w += t0.w;
                i1.x += t1.x; i1.y += t1.y; i1.z += t1.z; i1.w += t1.w;
                bf16x8 af = pack2(i0, i1);
                a0 = MFMA16(af, wvf[0][ks], a0);
                a1 = MFMA16(af, wvf[1][ks], a1);
            }
#pragma unroll
            for (int r = 0; r < 4; ++r) {
                const float wr = w_s[m * 16 + quad * 4 + r];  // LDS broadcast
                o0 += wr * tanh_fast(a0[r] + bvf[0]);
                o1 += wr * tanh_fast(a1[r] + bvf[1]);
            }
        }
        // reduce over the 4 row-groups (lanes l, l+16, l+32, l+48 share a col)
        o0 += __shfl_xor(o0, 16); o0 += __shfl_xor(o0, 32);
        o1 += __shfl_xor(o1, 16); o1 += __shfl_xor(o1, 32);
        if (lane < 16) {
            out[u * D_EMB + (2 * wv + 0) * 16 + lane] = o0;
            out[u * D_EMB + (2 * wv + 1) * 16 + lane] = o1;
        }
        __syncthreads();  // its/ots/w4/q_s reused next user
    }
}

extern "C" void kernel_launch(void* const* d_in, const int* in_sizes, int n_in,
                              void* d_out, int out_size, void* d_ws, size_t ws_size,
                              hipStream_t stream) {
    const float* item_table = (const float*)d_in[0];
    const float* opin_table = (const float*)d_in[1];
    const float* user_emb   = (const float*)d_in[2];
    const float* attr       = (const float*)d_in[3];
    const float* Wq = (const float*)d_in[4];
    const float* bq = (const float*)d_in[5];
    const float* Wk = (const float*)d_in[6];
    const float* bk = (const float*)d_in[7];
    const float* Wv = (const float*)d_in[8];
    const float* bv = (const float*)d_in[9];
    const int* item_seqs = (const int*)d_in[10];
    const int* opin_seqs = (const int*)d_in[11];
    float* out = (float*)d_out;

    const int U = in_sizes[2] / D_EMB;   // 10000
    const int grid = (U + UPB - 1) / UPB;
    finerec_fused<<<grid, 256, 0, stream>>>(item_table, opin_table, user_emb, attr,
                                            Wq, bq, Wk, bk, Wv, bv,
                                            item_seqs, opin_seqs, out, U);
}